// Round 5
// baseline (174.612 us; speedup 1.0000x reference)
//
#include <hip/hip_runtime.h>

// SA_Head: B=4, S=4096, E=256, H=64
//   out = softmax((emb@wq)(emb@wk)^T / 16) (emb@wv)
// R9: occupancy fix via register diet (NOT launch_bounds cap - R8 showed
// forcing 128 spills: CSV VGPR_Count excludes AGPRs, true R6 usage was
// 112+64=176 -> 2 waves/SIMD). Back to proven R6 16x16 structure, but each
// block now covers 32 q (qf 16 regs, oacc 32, lacc 2), V single-buffered.
// Working set ~110 regs -> 4 waves/SIMD naturally; grid 1024 = 4 blocks/CU,
// one round. Split-K x2, 32 tt x 64 keys per block.
// (R6: K dbuf prefetch, XCD swizzle, cvt_pk packing, setprio, [q][h] b128
//  epilogue. R4 base: no-max softmax |s|<=4, S^T-form QK keeps P in
//  registers, V pre-transposed vbt[h][s], zero-LDS K-loop.)

typedef short short4v __attribute__((ext_vector_type(4)));
typedef short short8v __attribute__((ext_vector_type(8)));
typedef float floatx4 __attribute__((ext_vector_type(4)));
typedef unsigned short u16;
typedef unsigned int u32;

#define SEQ 4096
#define EMB 256
#define HD 64
#define PADA 264   // u16 stride for proj A tile
#define OSTR 68    // f32 stride for attn epilogue O[q][h] tile

static __device__ __forceinline__ u16 f2bf(float x) {
    union { float f; unsigned u; } v; v.f = x;
    unsigned r = v.u + 0x7FFFu + ((v.u >> 16) & 1u);
    return (u16)(r >> 16);
}

static __device__ __forceinline__ u32 cvt_pk_bf16(float a, float b) {
    u32 r;
    asm("v_cvt_pk_bf16_f32 %0, %1, %2" : "=v"(r) : "v"(a), "v"(b));
    return r;
}

static __device__ __forceinline__ short4v pack_bf4(float a, float b, float c, float d) {
    union { u32 u[2]; short4v s; } x;
    x.u[0] = cvt_pk_bf16(a, b);
    x.u[1] = cvt_pk_bf16(c, d);
    return x.s;
}

// ---------------- W prep: fragment-major Wt --------------------------------------
// wt element order: ((nt*8+kc)*64 + lane)*8 + j  (u16), holding
// W[e=kc*32+(lane>>4)*8+j][col=nt*16+(lane&15)] * scale.  nt: 0..11 (q|k|v x4).
__global__ __launch_bounds__(256) void prep_w(
    const float* __restrict__ wk, const float* __restrict__ wq, const float* __restrict__ wv,
    u16* __restrict__ wt) {
    const int nt = blockIdx.x;   // 0..11
    const int t = threadIdx.x;
#pragma unroll
    for (int ss = 0; ss < 2; ++ss) {
        int slot = t + ss * 256;          // 0..511
        int kc = slot >> 6, lane = slot & 63;
        int ln15 = lane & 15, lq = lane >> 4;
        int cg = nt * 16 + ln15;
        int mat = cg >> 6, col = cg & 63;
        const float* W = (mat == 0) ? wq : (mat == 1) ? wk : wv;
        const float s = (mat == 0) ? 0.0625f * 1.44269504088896f : 1.0f;
        u32 w4[4];
#pragma unroll
        for (int p = 0; p < 2; ++p) {
#pragma unroll
            for (int d = 0; d < 2; ++d) {
                int e0 = kc * 32 + lq * 8 + p * 4 + d * 2;
                u16 lo = f2bf(W[(e0 + 0) * HD + col] * s);
                u16 hi = f2bf(W[(e0 + 1) * HD + col] * s);
                w4[p * 2 + d] = (u32)lo | ((u32)hi << 16);
            }
        }
        u32* dst = (u32*)wt + ((size_t)(nt * 8 + kc) * 64 + lane) * 4;
        *(uint4*)dst = make_uint4(w4[0], w4[1], w4[2], w4[3]);
    }
}

// ---------------- projection GEMM: [16384,256]@[256,192] bf16 MFMA ----------------
// grid 1024 x 256; 16 rows/block; wave w covers ntiles 3w..3w+2; v -> vbt[h][s].
__global__ __launch_bounds__(256) void proj_mfma(
    const float* __restrict__ emb, const u16* __restrict__ wt,
    u16* __restrict__ qb, u16* __restrict__ kb, u16* __restrict__ vbt) {
    __shared__ u16 a_s[16 * PADA];
    const int t = threadIdx.x;
    const int lane = t & 63;
    const int wave = t >> 6;
    const int ln15 = lane & 15;
    const int lq = lane >> 4;
    const size_t row0 = (size_t)blockIdx.x * 16;

    // coalesced staging: flat float4 f = t + c*256 -> row f>>6, cols (f&63)*4
#pragma unroll
    for (int c = 0; c < 4; ++c) {
        int f = t + c * 256;
        int row = f >> 6, e4 = (f & 63) * 4;
        float4 v = *(const float4*)(emb + (row0 + row) * EMB + e4);
        u32 lo = cvt_pk_bf16(v.x, v.y);
        u32 hi = cvt_pk_bf16(v.z, v.w);
        *(uint2*)&a_s[row * PADA + e4] = make_uint2(lo, hi);
    }
    __syncthreads();

    floatx4 acc[3];
#pragma unroll
    for (int j = 0; j < 3; ++j) {
        floatx4 z = { 0.f, 0.f, 0.f, 0.f };
        acc[j] = z;
    }

#pragma unroll
    for (int kc = 0; kc < 8; ++kc) {
        short8v a = *(const short8v*)&a_s[ln15 * PADA + kc * 32 + lq * 8];
#pragma unroll
        for (int j = 0; j < 3; ++j) {
            short8v b = *(const short8v*)(wt + (((size_t)(wave * 3 + j) * 8 + kc) * 64 + lane) * 8);
            acc[j] = __builtin_amdgcn_mfma_f32_16x16x32_bf16(a, b, acc[j], 0, 0, 0);
        }
    }

#pragma unroll
    for (int j = 0; j < 3; ++j) {
        int cg = (wave * 3 + j) * 16 + ln15;
        int mat = cg >> 6, col = cg & 63;
        if (mat < 2) {
            u16* O = (mat == 0) ? qb : kb;
#pragma unroll
            for (int r = 0; r < 4; ++r)
                O[(row0 + lq * 4 + r) * HD + col] = f2bf(acc[j][r]);
        } else {
            // vbt[(b*64+col)*4096 + s], s = (row0&4095)+lq*4+r : 8B contiguous
            u32 lo = cvt_pk_bf16(acc[j][0], acc[j][1]);
            u32 hi = cvt_pk_bf16(acc[j][2], acc[j][3]);
            size_t bidx = row0 >> 12;
            size_t sl = (row0 & 4095) + lq * 4;
            *(uint2*)&vbt[(bidx * 64 + col) * SEQ + sl] = make_uint2(lo, hi);
        }
    }
}

// ---------------- flash attention, split-K x2, 32-q blocks, zero-LDS loop ---------
// part = b*256 + qblk*2 + split; 4 waves; wave w owns keys [kw0+16w, +16).
// S^T = K.Q^T (16x16x32, nt=2 q-tiles); P = exp2(S^T) in-register;
// O^T += V^T.P (16x16x16).  K double-buffered; V issued at step top.

template <bool PF>
static __device__ __forceinline__ void attn_step(
    const int tt, const int split, const int wave, const int ln15, const int lq,
    const u16* __restrict__ kpb, const u16* __restrict__ vpb,
    const short8v (&qf)[2][2], const short8v k0c, const short8v k1c,
    short8v& k0n, short8v& k1n,
    floatx4 (&oacc)[4][2], float (&lacc)[2]) {
    const int kw = (split * 32 + tt) * 64 + wave * 16;   // wave's 16 keys

    // V^T A-frags for THIS tt: issue first, consumed last (covered by QK+exp)
    short4v vf[4];
#pragma unroll
    for (int ht = 0; ht < 4; ++ht)
        vf[ht] = *(const short4v*)(vpb + (size_t)(ht * 16 + ln15) * SEQ + kw + lq * 4);

    // prefetch NEXT tt's K frags into the other buffer
    if (PF) {
        const int kwn = kw + 64;
        k0n = *(const short8v*)(kpb + (size_t)(kwn + ln15) * HD + lq * 8);
        k1n = *(const short8v*)(kpb + (size_t)(kwn + ln15) * HD + 32 + lq * 8);
    }

    // S^T tiles: D[m=key][n=qrow], col=ln15=qrow, row=lq*4+r=key
    floatx4 s[2];
    __builtin_amdgcn_s_setprio(1);
#pragma unroll
    for (int nt = 0; nt < 2; ++nt) {
        floatx4 z = { 0.f, 0.f, 0.f, 0.f };
        s[nt] = __builtin_amdgcn_mfma_f32_16x16x32_bf16(k0c, qf[nt][0], z, 0, 0, 0);
        s[nt] = __builtin_amdgcn_mfma_f32_16x16x32_bf16(k1c, qf[nt][1], s[nt], 0, 0, 0);
    }
    __builtin_amdgcn_s_setprio(0);

    // P = exp2(S^T): C-layout == 16x16x16 B-layout, stays in registers
    short4v pf[2];
#pragma unroll
    for (int nt = 0; nt < 2; ++nt) {
        float p0 = __builtin_amdgcn_exp2f(s[nt][0]);
        float p1 = __builtin_amdgcn_exp2f(s[nt][1]);
        float p2 = __builtin_amdgcn_exp2f(s[nt][2]);
        float p3 = __builtin_amdgcn_exp2f(s[nt][3]);
        lacc[nt] += (p0 + p1) + (p2 + p3);
        pf[nt] = pack_bf4(p0, p1, p2, p3);
    }

    // O^T += V^T . P  (16x16x16, k = wave's 16 keys)
    __builtin_amdgcn_s_setprio(1);
#pragma unroll
    for (int ht = 0; ht < 4; ++ht)
#pragma unroll
        for (int nt = 0; nt < 2; ++nt)
            oacc[ht][nt] = __builtin_amdgcn_mfma_f32_16x16x16bf16_1k(
                vf[ht], pf[nt], oacc[ht][nt], 0, 0, 0);
    __builtin_amdgcn_s_setprio(0);
}

__global__ __launch_bounds__(256) void attn_kernel(
    const u16* __restrict__ qb, const u16* __restrict__ kb, const u16* __restrict__ vbt,
    float* __restrict__ po, float* __restrict__ pml) {
    __shared__ float ored[32 * OSTR];   // O[q][h], stride OSTR
    __shared__ float lred[4 * 32];

    const int t = threadIdx.x;
    const int lane = t & 63;
    const int wave = t >> 6;
    const int ln15 = lane & 15;
    const int lq = lane >> 4;

    // XCD-aware swizzle (1024 blocks, 1024%8==0 -> bijective): XCD x handles
    // parts [x*128, x*128+128) -> half a batch's K/V (~1MB) per XCD L2.
    const int part = ((blockIdx.x & 7) << 7) | (blockIdx.x >> 3);
    const int b = part >> 8;
    const int qblk = (part >> 1) & 127;
    const int split = part & 1;
    const int q0 = qblk * 32;

    const u16* __restrict__ qpb = qb + ((size_t)b * SEQ + q0) * HD;
    const u16* __restrict__ kpb = kb + (size_t)b * SEQ * HD;
    const u16* __restrict__ vpb = vbt + (size_t)b * HD * SEQ;

    // Q B-frags (loop-invariant): qf[nt][half] = Q[q0+nt*16+ln15][half*32+lq*8 ..+7]
    short8v qf[2][2];
#pragma unroll
    for (int nt = 0; nt < 2; ++nt)
#pragma unroll
        for (int h = 0; h < 2; ++h)
            qf[nt][h] = *(const short8v*)(qpb + (size_t)(nt * 16 + ln15) * HD + h * 32 + lq * 8);

    floatx4 oacc[4][2];
#pragma unroll
    for (int ht = 0; ht < 4; ++ht)
#pragma unroll
        for (int nt = 0; nt < 2; ++nt) {
            floatx4 z = { 0.f, 0.f, 0.f, 0.f };
            oacc[ht][nt] = z;
        }
    float lacc[2] = { 0.f, 0.f };

    // prologue: K frags for tt=0
    short8v kA0, kA1, kB0, kB1;
    {
        const int kw0 = (split * 32) * 64 + wave * 16;
        kA0 = *(const short8v*)(kpb + (size_t)(kw0 + ln15) * HD + lq * 8);
        kA1 = *(const short8v*)(kpb + (size_t)(kw0 + ln15) * HD + 32 + lq * 8);
    }

    // 32 tt steps, 2 per iteration, static buffer alternation; final PF=false.
#pragma unroll 1
    for (int tth = 0; tth < 15; ++tth) {
        attn_step<true>(2 * tth,     split, wave, ln15, lq, kpb, vpb, qf,
                        kA0, kA1, kB0, kB1, oacc, lacc);
        attn_step<true>(2 * tth + 1, split, wave, ln15, lq, kpb, vpb, qf,
                        kB0, kB1, kA0, kA1, oacc, lacc);
    }
    attn_step<true >(30, split, wave, ln15, lq, kpb, vpb, qf,
                     kA0, kA1, kB0, kB1, oacc, lacc);
    attn_step<false>(31, split, wave, ln15, lq, kpb, vpb, qf,
                     kB0, kB1, kA0, kA1, oacc, lacc);

    // ---- epilogue: cross-wave reduce (once per block) ----
#pragma unroll
    for (int nt = 0; nt < 2; ++nt) {
        lacc[nt] += __shfl_xor(lacc[nt], 16);
        lacc[nt] += __shfl_xor(lacc[nt], 32);
    }
    if (lq == 0) {
#pragma unroll
        for (int nt = 0; nt < 2; ++nt)
            lred[wave * 32 + nt * 16 + ln15] = lacc[nt];
    }

    // O[q][h] layout: oacc[ht][nt][r] -> row q=nt*16+ln15, col h=ht*16+lq*4+r
    // => full float4 (b128) LDS ops in the serial reduce.
    for (int s4 = 0; s4 < 4; ++s4) {
        if (wave == s4) {
#pragma unroll
            for (int nt = 0; nt < 2; ++nt)
#pragma unroll
                for (int ht = 0; ht < 4; ++ht) {
                    int idx = (nt * 16 + ln15) * OSTR + ht * 16 + lq * 4;
                    if (s4 == 0) {
                        *(floatx4*)&ored[idx] = oacc[ht][nt];
                    } else {
                        floatx4 old = *(floatx4*)&ored[idx];
                        old += oacc[ht][nt];
                        *(floatx4*)&ored[idx] = old;
                    }
                }
        }
        __syncthreads();
    }

    // write po[part][q][h] (coalesced float4) and combined l
    float* __restrict__ pob = po + (size_t)part * 2048;
#pragma unroll
    for (int i = 0; i < 2; ++i) {
        int f4 = t + i * 256;             // 0..511
        int q = f4 >> 4, h4 = (f4 & 15) * 4;
        *(float4*)&pob[q * HD + h4] = *(float4*)&ored[q * OSTR + h4];
    }
    if (t < 32)
        pml[part * 32 + t] = lred[t] + lred[32 + t] + lred[64 + t] + lred[96 + t];
}

// ---------------- split reduction: sum 2 splits, normalize (pure f4 stream) -------
__global__ __launch_bounds__(256) void reduce_kernel(
    const float* __restrict__ po, const float* __restrict__ pml,
    float* __restrict__ out) {
    __shared__ float ls[32];
    const int t = threadIdx.x;
    const int bq = blockIdx.x;           // b = bq>>7, qblk = bq&127
    const int part0 = bq * 2;

    if (t < 32)
        ls[t] = pml[(part0 + 0) * 32 + t] + pml[(part0 + 1) * 32 + t];
    __syncthreads();

    const float* __restrict__ p0 = po + (size_t)(part0 + 0) * 2048;
    const float* __restrict__ p1 = po + (size_t)(part0 + 1) * 2048;
    float* __restrict__ ob = out + ((size_t)(bq >> 7) * SEQ + (size_t)(bq & 127) * 32) * HD;

#pragma unroll
    for (int i = 0; i < 2; ++i) {
        int f4 = t + i * 256;            // 0..511
        int f = f4 * 4;
        int q = f4 >> 4;
        float4 a = *(const float4*)&p0[f];
        float4 c = *(const float4*)&p1[f];
        float inv = 1.0f / ls[q];
        float4 r;
        r.x = (a.x + c.x) * inv;
        r.y = (a.y + c.y) * inv;
        r.z = (a.z + c.z) * inv;
        r.w = (a.w + c.w) * inv;
        *(float4*)&ob[f] = r;
    }
}

extern "C" void kernel_launch(void* const* d_in, const int* in_sizes, int n_in,
                              void* d_out, int out_size, void* d_ws, size_t ws_size,
                              hipStream_t stream) {
    const float* emb = (const float*)d_in[0];
    const float* wk  = (const float*)d_in[1];
    const float* wq  = (const float*)d_in[2];
    const float* wv  = (const float*)d_in[3];

    // ws: qb 2M @0, kb 2M @2M, vbt 2M @4M, wt 96K @6M, po 8M @6.25M, pml 128K @22.25M
    u16* qb  = (u16*)d_ws;
    u16* kb  = (u16*)((char*)d_ws + (size_t)2 * 1024 * 1024);
    u16* vbt = (u16*)((char*)d_ws + (size_t)4 * 1024 * 1024);
    u16* wt  = (u16*)((char*)d_ws + (size_t)6 * 1024 * 1024);
    float* po  = (float*)((char*)d_ws + (size_t)6 * 1024 * 1024 + 256 * 1024);
    float* pml = (float*)((char*)d_ws + (size_t)22 * 1024 * 1024 + 256 * 1024);
    float* out = (float*)d_out;

    prep_w<<<12, 256, 0, stream>>>(wk, wq, wv, wt);
    proj_mfma<<<1024, 256, 0, stream>>>(emb, wt, qb, kb, vbt);
    attn_kernel<<<1024, 256, 0, stream>>>(qb, kb, vbt, po, pml);
    reduce_kernel<<<512, 256, 0, stream>>>(po, pml, out);
}

// Round 6
// 112.726 us; speedup vs baseline: 1.5490x; 1.5490x over previous
//
#include <hip/hip_runtime.h>

// SA_Head: B=4, S=4096, E=256, H=64
//   out = softmax((emb@wq)(emb@wk)^T / 16) (emb@wv)
// R10: attn was L2-TRANSACTION-bound, not latency-bound (R6: 4080 cyc/tt vs
// ~300 cyc issue work; per-lane scattered fragment loads = ~770 L2
// transactions/CU/tt). Fix: stage K and V^T tiles (8KB each) in LDS per tt
// via coalesced 16B/lane loads (12x fewer transactions), XOR-swizzled
// (chunk^=row&7 at 16B granule) so b128/8B frag reads are bank-minimal.
// T14 split staging: global->reg at tt top, ds_write after compute, one
// barrier/tt, double-buffered. Compute/softmax/epilogue = R6 verbatim.
// ored aliases staging LDS (33KB total).
// (R6 base: split-K x2 grid 512, XCD swizzle, no-max softmax |s|<=4,
//  S^T-form QK keeps P in registers, V pre-transposed vbt[h][s].)

typedef short short4v __attribute__((ext_vector_type(4)));
typedef short short8v __attribute__((ext_vector_type(8)));
typedef float floatx4 __attribute__((ext_vector_type(4)));
typedef unsigned short u16;
typedef unsigned int u32;

#define SEQ 4096
#define EMB 256
#define HD 64
#define PADA 264   // u16 stride for proj A tile
#define OSTR 68    // f32 stride for attn epilogue O[q][h] tile

static __device__ __forceinline__ u16 f2bf(float x) {
    union { float f; unsigned u; } v; v.f = x;
    unsigned r = v.u + 0x7FFFu + ((v.u >> 16) & 1u);
    return (u16)(r >> 16);
}

static __device__ __forceinline__ u32 cvt_pk_bf16(float a, float b) {
    u32 r;
    asm("v_cvt_pk_bf16_f32 %0, %1, %2" : "=v"(r) : "v"(a), "v"(b));
    return r;
}

static __device__ __forceinline__ short4v pack_bf4(float a, float b, float c, float d) {
    union { u32 u[2]; short4v s; } x;
    x.u[0] = cvt_pk_bf16(a, b);
    x.u[1] = cvt_pk_bf16(c, d);
    return x.s;
}

// ---------------- W prep: fragment-major Wt --------------------------------------
__global__ __launch_bounds__(256) void prep_w(
    const float* __restrict__ wk, const float* __restrict__ wq, const float* __restrict__ wv,
    u16* __restrict__ wt) {
    const int nt = blockIdx.x;   // 0..11
    const int t = threadIdx.x;
#pragma unroll
    for (int ss = 0; ss < 2; ++ss) {
        int slot = t + ss * 256;          // 0..511
        int kc = slot >> 6, lane = slot & 63;
        int ln15 = lane & 15, lq = lane >> 4;
        int cg = nt * 16 + ln15;
        int mat = cg >> 6, col = cg & 63;
        const float* W = (mat == 0) ? wq : (mat == 1) ? wk : wv;
        const float s = (mat == 0) ? 0.0625f * 1.44269504088896f : 1.0f;
        u32 w4[4];
#pragma unroll
        for (int p = 0; p < 2; ++p) {
#pragma unroll
            for (int d = 0; d < 2; ++d) {
                int e0 = kc * 32 + lq * 8 + p * 4 + d * 2;
                u16 lo = f2bf(W[(e0 + 0) * HD + col] * s);
                u16 hi = f2bf(W[(e0 + 1) * HD + col] * s);
                w4[p * 2 + d] = (u32)lo | ((u32)hi << 16);
            }
        }
        u32* dst = (u32*)wt + ((size_t)(nt * 8 + kc) * 64 + lane) * 4;
        *(uint4*)dst = make_uint4(w4[0], w4[1], w4[2], w4[3]);
    }
}

// ---------------- projection GEMM: [16384,256]@[256,192] bf16 MFMA ----------------
__global__ __launch_bounds__(256) void proj_mfma(
    const float* __restrict__ emb, const u16* __restrict__ wt,
    u16* __restrict__ qb, u16* __restrict__ kb, u16* __restrict__ vbt) {
    __shared__ u16 a_s[16 * PADA];
    const int t = threadIdx.x;
    const int lane = t & 63;
    const int wave = t >> 6;
    const int ln15 = lane & 15;
    const int lq = lane >> 4;
    const size_t row0 = (size_t)blockIdx.x * 16;

#pragma unroll
    for (int c = 0; c < 4; ++c) {
        int f = t + c * 256;
        int row = f >> 6, e4 = (f & 63) * 4;
        float4 v = *(const float4*)(emb + (row0 + row) * EMB + e4);
        u32 lo = cvt_pk_bf16(v.x, v.y);
        u32 hi = cvt_pk_bf16(v.z, v.w);
        *(uint2*)&a_s[row * PADA + e4] = make_uint2(lo, hi);
    }
    __syncthreads();

    floatx4 acc[3];
#pragma unroll
    for (int j = 0; j < 3; ++j) {
        floatx4 z = { 0.f, 0.f, 0.f, 0.f };
        acc[j] = z;
    }

#pragma unroll
    for (int kc = 0; kc < 8; ++kc) {
        short8v a = *(const short8v*)&a_s[ln15 * PADA + kc * 32 + lq * 8];
#pragma unroll
        for (int j = 0; j < 3; ++j) {
            short8v b = *(const short8v*)(wt + (((size_t)(wave * 3 + j) * 8 + kc) * 64 + lane) * 8);
            acc[j] = __builtin_amdgcn_mfma_f32_16x16x32_bf16(a, b, acc[j], 0, 0, 0);
        }
    }

#pragma unroll
    for (int j = 0; j < 3; ++j) {
        int cg = (wave * 3 + j) * 16 + ln15;
        int mat = cg >> 6, col = cg & 63;
        if (mat < 2) {
            u16* O = (mat == 0) ? qb : kb;
#pragma unroll
            for (int r = 0; r < 4; ++r)
                O[(row0 + lq * 4 + r) * HD + col] = f2bf(acc[j][r]);
        } else {
            u32 lo = cvt_pk_bf16(acc[j][0], acc[j][1]);
            u32 hi = cvt_pk_bf16(acc[j][2], acc[j][3]);
            size_t bidx = row0 >> 12;
            size_t sl = (row0 & 4095) + lq * 4;
            *(uint2*)&vbt[(bidx * 64 + col) * SEQ + sl] = make_uint2(lo, hi);
        }
    }
}

// ---------------- flash attention: LDS-staged tiles, split-K x2 -------------------
// part = b*128 + qt*2 + split; 4 waves; wave w owns keys [tile + 16w, +16).
// Per tt: stage K[64 keys][64 dims] and V^T[64 h][64 keys] into LDS
// (coalesced, XOR-swizzled), then S^T = K.Q^T (16x16x32), P = exp2 in-reg,
// O^T += V^T.P (16x16x16).  Double-buffered, one barrier per tt.

__global__ __launch_bounds__(256) void attn_kernel(
    const u16* __restrict__ qb, const u16* __restrict__ kb, const u16* __restrict__ vbt,
    float* __restrict__ po, float* __restrict__ pml) {
    // smem[buf*2+0] = K tile, smem[buf*2+1] = V tile; each 64 rows x 128B.
    // 16B chunk c of row r stored at chunk (c ^ (r&7)).  Re-used as ored[].
    __shared__ __align__(16) u16 smem[4][64 * 64];
    __shared__ float lred[4 * 64];

    const int t = threadIdx.x;
    const int lane = t & 63;
    const int wave = t >> 6;
    const int ln15 = lane & 15;
    const int lq = lane >> 4;

    // XCD-aware swizzle (512 blocks, 512%8==0 -> bijective)
    const int part = ((blockIdx.x & 7) << 6) | (blockIdx.x >> 3);
    const int b = part >> 7;
    const int qt = (part >> 1) & 63;
    const int split = part & 1;
    const int q0 = qt * 64;

    const u16* __restrict__ qpb = qb + ((size_t)b * SEQ + q0) * HD;
    const u16* __restrict__ kpb = kb + (size_t)b * SEQ * HD;
    const u16* __restrict__ vpb = vbt + (size_t)b * HD * SEQ;

    // Q B-frags (loop-invariant)
    short8v qf[4][2];
#pragma unroll
    for (int nt = 0; nt < 4; ++nt)
#pragma unroll
        for (int h = 0; h < 2; ++h)
            qf[nt][h] = *(const short8v*)(qpb + (size_t)(nt * 16 + ln15) * HD + h * 32 + lq * 8);

    floatx4 oacc[4][4];
#pragma unroll
    for (int ht = 0; ht < 4; ++ht)
#pragma unroll
        for (int nt = 0; nt < 4; ++nt) {
            floatx4 z = { 0.f, 0.f, 0.f, 0.f };
            oacc[ht][nt] = z;
        }
    float lacc[4] = { 0.f, 0.f, 0.f, 0.f };

    // staging geometry: flat f = t (+256): row = f>>3 (K: key row, V: h row),
    // chunk = f&7 (16B units within the 128B row).  LDS chunk = chunk^(row&7).
    const int r0 = t >> 3, c0 = t & 7;
    const int r1 = (t + 256) >> 3, c1 = t & 7;
    const int sw0 = r0 * 64 + ((c0 ^ (r0 & 7)) * 8);
    const int sw1 = r1 * 64 + ((c1 ^ (r1 & 7)) * 8);

    // frag read offsets (u16 units), invariant parts
    const int krow = wave * 16 + ln15;               // K row for this lane
    const int ksw_lo = krow * 64 + (((0 + lq) ^ (ln15 & 7)) * 8);
    const int ksw_hi = krow * 64 + (((4 + lq) ^ (ln15 & 7)) * 8);
    const int vch = wave * 2 + (lq >> 1);            // V 16B-chunk wanted
    const int voff = ((vch ^ (ln15 & 7)) * 8) + (lq & 1) * 4;

    uint4 ka, kb4, va, vb4;
    {   // prologue: stage tile 0 into buf 0
        const int kwb = (split * 32) * 64;
        ka  = *(const uint4*)(kpb + (size_t)(kwb + r0) * HD + c0 * 8);
        kb4 = *(const uint4*)(kpb + (size_t)(kwb + r1) * HD + c1 * 8);
        va  = *(const uint4*)(vpb + (size_t)r0 * SEQ + kwb + c0 * 8);
        vb4 = *(const uint4*)(vpb + (size_t)r1 * SEQ + kwb + c1 * 8);
        *(uint4*)(&smem[0][0] + sw0) = ka;
        *(uint4*)(&smem[0][0] + sw1) = kb4;
        *(uint4*)(&smem[1][0] + sw0) = va;
        *(uint4*)(&smem[1][0] + sw1) = vb4;
    }
    __syncthreads();

#pragma unroll 1
    for (int tt = 0; tt < 32; ++tt) {
        const int buf = tt & 1;
        // issue next tile's global loads (latency hidden under compute)
        if (tt < 31) {
            const int kwb = (split * 32 + tt + 1) * 64;
            ka  = *(const uint4*)(kpb + (size_t)(kwb + r0) * HD + c0 * 8);
            kb4 = *(const uint4*)(kpb + (size_t)(kwb + r1) * HD + c1 * 8);
            va  = *(const uint4*)(vpb + (size_t)r0 * SEQ + kwb + c0 * 8);
            vb4 = *(const uint4*)(vpb + (size_t)r1 * SEQ + kwb + c1 * 8);
        }

        const u16* kt = &smem[buf * 2 + 0][0];
        const u16* vt = &smem[buf * 2 + 1][0];

        // V^T A-frags from LDS (8B each, swizzled)
        short4v vf[4];
#pragma unroll
        for (int ht = 0; ht < 4; ++ht)
            vf[ht] = *(const short4v*)(vt + (ht * 16 + ln15) * 64 + voff);

        // K A-frags from LDS (16B, swizzled)
        short8v k0 = *(const short8v*)(kt + ksw_lo);
        short8v k1 = *(const short8v*)(kt + ksw_hi);

        // S^T tiles: D[m=key][n=qrow]
        floatx4 s[4];
        __builtin_amdgcn_s_setprio(1);
#pragma unroll
        for (int nt = 0; nt < 4; ++nt) {
            floatx4 z = { 0.f, 0.f, 0.f, 0.f };
            s[nt] = __builtin_amdgcn_mfma_f32_16x16x32_bf16(k0, qf[nt][0], z, 0, 0, 0);
            s[nt] = __builtin_amdgcn_mfma_f32_16x16x32_bf16(k1, qf[nt][1], s[nt], 0, 0, 0);
        }
        __builtin_amdgcn_s_setprio(0);

        // P = exp2(S^T): C-layout == 16x16x16 B-layout, stays in registers
        short4v pf[4];
#pragma unroll
        for (int nt = 0; nt < 4; ++nt) {
            float p0 = __builtin_amdgcn_exp2f(s[nt][0]);
            float p1 = __builtin_amdgcn_exp2f(s[nt][1]);
            float p2 = __builtin_amdgcn_exp2f(s[nt][2]);
            float p3 = __builtin_amdgcn_exp2f(s[nt][3]);
            lacc[nt] += (p0 + p1) + (p2 + p3);
            pf[nt] = pack_bf4(p0, p1, p2, p3);
        }

        // O^T += V^T . P
        __builtin_amdgcn_s_setprio(1);
#pragma unroll
        for (int ht = 0; ht < 4; ++ht)
#pragma unroll
            for (int nt = 0; nt < 4; ++nt)
                oacc[ht][nt] = __builtin_amdgcn_mfma_f32_16x16x16bf16_1k(
                    vf[ht], pf[nt], oacc[ht][nt], 0, 0, 0);
        __builtin_amdgcn_s_setprio(0);

        // write next tile to the other LDS buffer (vmcnt drains here, T14)
        if (tt < 31) {
            u16* ktn = &smem[(buf ^ 1) * 2 + 0][0];
            u16* vtn = &smem[(buf ^ 1) * 2 + 1][0];
            *(uint4*)(ktn + sw0) = ka;
            *(uint4*)(ktn + sw1) = kb4;
            *(uint4*)(vtn + sw0) = va;
            *(uint4*)(vtn + sw1) = vb4;
        }
        __syncthreads();
    }

    // ---- epilogue: cross-wave reduce (once per block) ----
#pragma unroll
    for (int nt = 0; nt < 4; ++nt) {
        lacc[nt] += __shfl_xor(lacc[nt], 16);
        lacc[nt] += __shfl_xor(lacc[nt], 32);
    }
    if (lq == 0) {
#pragma unroll
        for (int nt = 0; nt < 4; ++nt)
            lred[wave * 64 + nt * 16 + ln15] = lacc[nt];
    }

    // O[q][h] reduce in LDS (aliases staging buffers; loop's final barrier
    // guarantees all tile reads done).
    float* ored = (float*)&smem[0][0];
    for (int s4 = 0; s4 < 4; ++s4) {
        if (wave == s4) {
#pragma unroll
            for (int nt = 0; nt < 4; ++nt)
#pragma unroll
                for (int ht = 0; ht < 4; ++ht) {
                    int idx = (nt * 16 + ln15) * OSTR + ht * 16 + lq * 4;
                    if (s4 == 0) {
                        *(floatx4*)&ored[idx] = oacc[ht][nt];
                    } else {
                        floatx4 old = *(floatx4*)&ored[idx];
                        old += oacc[ht][nt];
                        *(floatx4*)&ored[idx] = old;
                    }
                }
        }
        __syncthreads();
    }

    // write po[part][q][h] (coalesced float4) and combined l
    float* __restrict__ pob = po + (size_t)part * 4096;
#pragma unroll
    for (int i = 0; i < 4; ++i) {
        int f4 = t + i * 256;             // 0..1023
        int q = f4 >> 4, h4 = (f4 & 15) * 4;
        *(float4*)&pob[q * HD + h4] = *(float4*)&ored[q * OSTR + h4];
    }
    if (t < 64)
        pml[part * 64 + t] = lred[t] + lred[64 + t] + lred[128 + t] + lred[192 + t];
}

// ---------------- split reduction: sum 2 splits, normalize (pure f4 stream) -------
__global__ __launch_bounds__(256) void reduce_kernel(
    const float* __restrict__ po, const float* __restrict__ pml,
    float* __restrict__ out) {
    __shared__ float ls[64];
    const int t = threadIdx.x;
    const int part0 = blockIdx.x * 2;
    const int bq = blockIdx.x;           // b = bq>>6, qt = bq&63

    if (t < 64)
        ls[t] = pml[(part0 + 0) * 64 + t] + pml[(part0 + 1) * 64 + t];
    __syncthreads();

    const float* __restrict__ p0 = po + (size_t)(part0 + 0) * 4096;
    const float* __restrict__ p1 = po + (size_t)(part0 + 1) * 4096;
    float* __restrict__ ob = out + (((size_t)(bq >> 6) * SEQ + (size_t)(bq & 63) * 64)) * HD;

#pragma unroll
    for (int i = 0; i < 4; ++i) {
        int f4 = t + i * 256;            // 0..1023
        int f = f4 * 4;
        int q = f4 >> 4;
        float4 a = *(const float4*)&p0[f];
        float4 c = *(const float4*)&p1[f];
        float inv = 1.0f / ls[q];
        float4 r;
        r.x = (a.x + c.x) * inv;
        r.y = (a.y + c.y) * inv;
        r.z = (a.z + c.z) * inv;
        r.w = (a.w + c.w) * inv;
        *(float4*)&ob[f] = r;
    }
}

extern "C" void kernel_launch(void* const* d_in, const int* in_sizes, int n_in,
                              void* d_out, int out_size, void* d_ws, size_t ws_size,
                              hipStream_t stream) {
    const float* emb = (const float*)d_in[0];
    const float* wk  = (const float*)d_in[1];
    const float* wq  = (const float*)d_in[2];
    const float* wv  = (const float*)d_in[3];

    // ws: qb 2M @0, kb 2M @2M, vbt 2M @4M, wt 96K @6M, po 8M @6.25M, pml 128K @22.25M
    u16* qb  = (u16*)d_ws;
    u16* kb  = (u16*)((char*)d_ws + (size_t)2 * 1024 * 1024);
    u16* vbt = (u16*)((char*)d_ws + (size_t)4 * 1024 * 1024);
    u16* wt  = (u16*)((char*)d_ws + (size_t)6 * 1024 * 1024);
    float* po  = (float*)((char*)d_ws + (size_t)6 * 1024 * 1024 + 256 * 1024);
    float* pml = (float*)((char*)d_ws + (size_t)22 * 1024 * 1024 + 256 * 1024);
    float* out = (float*)d_out;

    prep_w<<<12, 256, 0, stream>>>(wk, wq, wv, wt);
    proj_mfma<<<1024, 256, 0, stream>>>(emb, wt, qb, kb, vbt);
    attn_kernel<<<512, 256, 0, stream>>>(qb, kb, vbt, po, pml);
    reduce_kernel<<<256, 256, 0, stream>>>(po, pml, out);
}